// Round 1
// 200.037 us; speedup vs baseline: 1.0748x; 1.0748x over previous
//
#include <hip/hip_runtime.h>
#include <hip/hip_bf16.h>

#define IN_F 1024
#define OUT_F 1024
#define QP 9                   // silu + 8 spline bases per input feature
#define KDIM (IN_F * QP)       // 9216
#define BM 256
#define BN 256
#define BK 32

typedef __attribute__((ext_vector_type(8)))  short short8;           // MFMA A/B frag (8 bf16)
typedef __attribute__((ext_vector_type(16))) float floatx16;         // 32x32 MFMA C/D frag
typedef __attribute__((ext_vector_type(8)))  unsigned short ushort8v;// 16B bf16 vector

__device__ __forceinline__ unsigned short f2bf(float f) {
    union { float f; unsigned u; } v; v.f = f;
    return (unsigned short)((v.u + 0x7FFF + ((v.u >> 16) & 1)) >> 16); // RNE
}
__device__ __forceinline__ float bf2f(unsigned short h) {
    union { unsigned u; float f; } v; v.u = ((unsigned)h) << 16;
    return v.f;
}

// ============ fused pack: A [B,KDIM] + W [OUT,KDIM], bf16; k = s*IN_F + i ============
// (unchanged from the 215 µs version)
__global__ __launch_bounds__(256) void pack_kernel(const float* __restrict__ x,
                                                   const float* __restrict__ bw,
                                                   const float* __restrict__ sw,
                                                   __hip_bfloat16* __restrict__ A,
                                                   __hip_bfloat16* __restrict__ W, int Bm) {
    const int nb_a = (Bm * IN_F / 8) / 256;
    if ((int)blockIdx.x < nb_a) {
        int t  = blockIdx.x * 256 + threadIdx.x;   // one thread = 8 features of one row
        int b  = t >> 7;
        int i0 = (t & 127) * 8;
        const float4* xr = (const float4*)(x + (size_t)b * IN_F + i0);
        float4 x0 = xr[0], x1 = xr[1];
        float xv[8] = {x0.x, x0.y, x0.z, x0.w, x1.x, x1.y, x1.z, x1.w};
        ushort8v ov[9];
#pragma unroll
        for (int e = 0; e < 8; ++e) {
            float v  = xv[e];
            float u  = (v + 1.0f) * 5.5f;
            float fj = floorf(u);
            int   j  = (int)fj;
            float tt = u - fj;
            float t2 = tt * tt, t3 = t2 * tt;
            float omt = 1.0f - tt;
            float w0 = omt * omt * omt * (1.0f / 6.0f);                           // q=j-3
            float w1 = (3.0f * t3 - 6.0f * t2 + 4.0f) * (1.0f / 6.0f);            // q=j-2
            float w2 = (-3.0f * t3 + 3.0f * t2 + 3.0f * tt + 1.0f) * (1.0f/6.0f); // q=j-1
            float w3 = t3 * (1.0f / 6.0f);                                        // q=j
            ov[0][e] = f2bf(v * __builtin_amdgcn_rcpf(1.0f + __expf(-v)));        // silu
#pragma unroll
            for (int q = 0; q < 8; ++q) {
                int d = j - q;
                float bv = (d == 3) ? w0 : (d == 2) ? w1 : (d == 1) ? w2 : (d == 0) ? w3 : 0.0f;
                ov[1 + q][e] = f2bf(bv);
            }
        }
        unsigned short* dst = (unsigned short*)A + (size_t)b * KDIM + i0;
#pragma unroll
        for (int s = 0; s < QP; ++s)
            *(ushort8v*)(dst + (size_t)s * IN_F) = ov[s];        // coalesced 16B
    } else {
        int t = ((int)blockIdx.x - nb_a) * 256 + threadIdx.x;    // one (o,i)
        unsigned short* dst = (unsigned short*)W + (size_t)(t >> 10) * KDIM + (t & 1023);
        dst[0] = f2bf(bw[t]);
        const float4* s4 = (const float4*)(sw + (size_t)t * 8);  // 32B contiguous/thread
        float4 lo = s4[0], hi = s4[1];
        dst[1 * IN_F] = f2bf(lo.x); dst[2 * IN_F] = f2bf(lo.y);
        dst[3 * IN_F] = f2bf(lo.z); dst[4 * IN_F] = f2bf(lo.w);
        dst[5 * IN_F] = f2bf(hi.x); dst[6 * IN_F] = f2bf(hi.y);
        dst[7 * IN_F] = f2bf(hi.z); dst[8 * IN_F] = f2bf(hi.w);  // coalesced across lanes
    }
}

// ============ split-K GEMM: 256x256 tile, BK=32, 3-deep LDS ring, counted vmcnt ======
// T3+T4 (counted-vmcnt pipeline) without vmcnt(0) in the main loop:
//   tile t -> ring buffer t%3. While computing tile t, issue tile t+2 into
//   buffer (t+2)%3 = (t-1)%3, whose last read finished before the barrier we
//   just passed -> provably race-free by barrier ordering alone.
//   Steady-state boundary wait: vmcnt(4) (tile t landed, t+1 in flight),
//   issued one full K-tile (~1000 cyc) after those loads went out -> ~no stall.
// LDS: 2-bit XOR granule swizzle (gpos = g ^ ((row>>1)&3)), applied on the
//   GLOBAL source address (gload_lds dest must stay linear, m104/m173) and on
//   the ds_read address -> every 8-lane b128 group hits all 32 banks once.
#define GLD(src, dst) __builtin_amdgcn_global_load_lds( \
        (const __attribute__((address_space(1))) void*)(src), \
        (__attribute__((address_space(3))) void*)(dst), 16, 0, 0)

__global__ __launch_bounds__(512, 2) void gemm_splitk(const __hip_bfloat16* __restrict__ A,
                                                      const __hip_bfloat16* __restrict__ W,
                                                      unsigned short* __restrict__ P,
                                                      int Bm, int splitk, int kslice) {
    __shared__ short sA[3][BM * BK];   // 3 x 16 KB
    __shared__ short sB[3][BN * BK];   // 3 x 16 KB  (96 KB total -> 1 block/CU)
    const int tid  = threadIdx.x;
    const int lane = tid & 63;
    const int wave = tid >> 6;
    const int r32  = lane & 31;
    const int half = lane >> 5;
    const int wm   = wave >> 2;        // 0..1 : wave rows 128
    const int wn   = wave & 3;         // 0..3 : wave cols 64

    // XCD-aware decode: (splitk/2) (n,z)-pairs per XCD -> each XCD's W working
    // set is 2 x 1.18 MB (L2-resident); each A panel touched by only 2 XCDs.
    const int b   = (int)blockIdx.x;
    const int xcd = b & 7, ii = b >> 3;
    const int pp  = xcd * (splitk >> 1) + (ii >> 4);
    const int xt  = pp & 3, zt = pp >> 2, yt = ii & 15;
    const int m0 = yt * BM, n0 = xt * BN, kb = zt * kslice;
    const int NT = kslice / BK;        // 72 (splitk=4) or 144 (splitk=2)

    const short* Ag = (const short*)A + (size_t)m0 * KDIM + kb;
    const short* Wg = (const short*)W + (size_t)n0 * KDIM + kb;

    // staging: 1024 16B-chunks per matrix per tile; chunk c -> (row=c>>2, gpos=c&3),
    // LDS dest linear (c*8 shorts); source granule pre-swizzled: (c&3)^((c>>3)&3)
    const int c0 = tid, c1 = 512 + tid;
    const int g0 = (c0 & 3) ^ ((c0 >> 3) & 3);
    const int g1 = (c1 & 3) ^ ((c1 >> 3) & 3);
    const short* pA0 = Ag + (size_t)(c0 >> 2) * KDIM + g0 * 8;
    const short* pA1 = Ag + (size_t)(c1 >> 2) * KDIM + g1 * 8;
    const short* pB0 = Wg + (size_t)(c0 >> 2) * KDIM + g0 * 8;
    const short* pB1 = Wg + (size_t)(c1 >> 2) * KDIM + g1 * 8;
    const int l0 = c0 * 8, l1 = c1 * 8;

    // fragment ds_read offsets (conflict-free under the 2-bit XOR swizzle)
    int offA[4][2], offB[2][2];
#pragma unroll
    for (int mi = 0; mi < 4; ++mi) {
        int row = wm * 128 + mi * 32 + r32;
        int sw  = (row >> 1) & 3;
#pragma unroll
        for (int kc = 0; kc < 2; ++kc)
            offA[mi][kc] = row * BK + (((kc * 2 + half) ^ sw) * 8);
    }
#pragma unroll
    for (int ni = 0; ni < 2; ++ni) {
        int row = wn * 64 + ni * 32 + r32;
        int sw  = (row >> 1) & 3;
#pragma unroll
        for (int kc = 0; kc < 2; ++kc)
            offB[ni][kc] = row * BK + (((kc * 2 + half) ^ sw) * 8);
    }

    floatx16 acc[4][2] = {};

#define STAGE(bi, koff) do { \
        GLD(pA0 + (koff), &sA[bi][l0]); \
        GLD(pA1 + (koff), &sA[bi][l1]); \
        GLD(pB0 + (koff), &sB[bi][l0]); \
        GLD(pB1 + (koff), &sB[bi][l1]); \
    } while (0)

    STAGE(0, 0);        // tile 0
    STAGE(1, BK);       // tile 1   (8 loads outstanding)

    int bi = 0;
    for (int t = 0; t < NT; ++t) {
        // boundary: own tile-t loads landed (vmcnt), own ds_reads of t-1 done
        // (lgkmcnt), then all-waves barrier -> collectively tile t is resident
        // and buffer (t-1)%3 is free for overwrite.
        if (t == NT - 1) asm volatile("s_waitcnt vmcnt(0) lgkmcnt(0)" ::: "memory");
        else             asm volatile("s_waitcnt vmcnt(4) lgkmcnt(0)" ::: "memory");
        __builtin_amdgcn_s_barrier();

        const short* sAb = &sA[bi][0];
        const short* sBb = &sB[bi][0];
        short8 aF[2][4], bF[2][2];
#pragma unroll
        for (int kc = 0; kc < 2; ++kc) {
#pragma unroll
            for (int mi = 0; mi < 4; ++mi) aF[kc][mi] = *(const short8*)(sAb + offA[mi][kc]);
#pragma unroll
            for (int ni = 0; ni < 2; ++ni) bF[kc][ni] = *(const short8*)(sBb + offB[ni][kc]);
        }

        if (t + 2 < NT) {                          // prefetch 2 tiles ahead
            int b2 = bi + 2; if (b2 >= 3) b2 -= 3;
            STAGE(b2, (t + 2) * BK);
        }

        __builtin_amdgcn_s_setprio(1);
#pragma unroll
        for (int kc = 0; kc < 2; ++kc)
#pragma unroll
            for (int mi = 0; mi < 4; ++mi)
#pragma unroll
                for (int ni = 0; ni < 2; ++ni)
                    acc[mi][ni] = __builtin_amdgcn_mfma_f32_32x32x16_bf16(
                        aF[kc][mi], bF[kc][ni], acc[mi][ni], 0, 0, 0);
        __builtin_amdgcn_s_setprio(0);

        if (++bi == 3) bi = 0;
    }
#undef STAGE

    // C/D layout (m74/m101-verified): col = lane&31, row = (reg&3) + 8*(reg>>2) + 4*(lane>>5)
    unsigned short* Pz = P + (size_t)zt * Bm * OUT_F;
#pragma unroll
    for (int mi = 0; mi < 4; ++mi)
#pragma unroll
        for (int ni = 0; ni < 2; ++ni)
#pragma unroll
            for (int r = 0; r < 16; ++r) {
                int row = (r & 3) + 8 * (r >> 2) + 4 * half;
                int gm  = m0 + wm * 128 + mi * 32 + row;
                Pz[(size_t)gm * OUT_F + n0 + wn * 64 + ni * 32 + r32] = f2bf(acc[mi][ni][r]);
            }
}

// ============ reduce: C = sum_j P_j (bf16 partials -> fp32 out), 8 elems/thread ====
__global__ __launch_bounds__(256) void reduce_kernel(const unsigned short* __restrict__ P,
                                                     float* __restrict__ C, int n, int s) {
    int t  = blockIdx.x * 256 + threadIdx.x;
    int i0 = t * 8;
    float o[8] = {0.f, 0.f, 0.f, 0.f, 0.f, 0.f, 0.f, 0.f};
    for (int j = 0; j < s; ++j) {
        ushort8v a = *(const ushort8v*)(P + (size_t)j * n + i0);
#pragma unroll
        for (int e = 0; e < 8; ++e) o[e] += bf2f(a[e]);
    }
    float4 o0, o1;
    o0.x = o[0]; o0.y = o[1]; o0.z = o[2]; o0.w = o[3];
    o1.x = o[4]; o1.y = o[5]; o1.z = o[6]; o1.w = o[7];
    *(float4*)(C + i0)     = o0;
    *(float4*)(C + i0 + 4) = o1;
}

// ---- fp32 fallback (tiny ws / unexpected shape) ----
__global__ __launch_bounds__(256) void fallback_kernel(const float* __restrict__ x,
                                                       const float* __restrict__ bw,
                                                       const float* __restrict__ sw,
                                                       const float* __restrict__ grid,
                                                       float* __restrict__ out, int Bm) {
    __shared__ float sv[256][QP + 1];
    int b = blockIdx.y;
    int o = blockIdx.x * 256 + threadIdx.x;
    float acc = 0.f;
    for (int ic = 0; ic < IN_F; ic += 256) {
        int i = ic + threadIdx.x;
        float v = x[(size_t)b * IN_F + i];
        float g[12];
        for (int j = 0; j < 12; ++j) g[j] = grid[j];
        float bb[11];
        for (int j = 0; j < 11; ++j) bb[j] = (v >= g[j] && v < g[j + 1]) ? 1.f : 0.f;
        for (int k = 1; k <= 3; ++k)
            for (int j = 0; j < 11 - k; ++j)
                bb[j] = (v - g[j]) / (g[j + k] - g[j] + 1e-8f) * bb[j]
                      + (g[j + k + 1] - v) / (g[j + k + 1] - g[j + 1] + 1e-8f) * bb[j + 1];
        __syncthreads();
        sv[threadIdx.x][0] = v / (1.f + __expf(-v));
        for (int q = 0; q < 8; ++q) sv[threadIdx.x][1 + q] = bb[q];
        __syncthreads();
        for (int ii = 0; ii < 256; ++ii) {
            int i2 = ic + ii;
            acc += sv[ii][0] * bw[(size_t)o * IN_F + i2];
            const float* swp = sw + ((size_t)o * IN_F + i2) * 8;
            for (int q = 0; q < 8; ++q) acc += sv[ii][1 + q] * swp[q];
        }
    }
    out[(size_t)b * OUT_F + o] = acc;
}

extern "C" void kernel_launch(void* const* d_in, const int* in_sizes, int n_in,
                              void* d_out, int out_size, void* d_ws, size_t ws_size,
                              hipStream_t stream) {
    const float* x    = (const float*)d_in[0];
    const float* bw   = (const float*)d_in[1];
    const float* sw   = (const float*)d_in[2];
    const float* grid = (const float*)d_in[3];
    float* out = (float*)d_out;

    const int Bm = in_sizes[0] / IN_F;                     // 4096
    const size_t a_bytes = (size_t)Bm * KDIM * sizeof(__hip_bfloat16);
    const size_t w_bytes = (size_t)OUT_F * KDIM * sizeof(__hip_bfloat16);

    int splitk = 4;                                        // 256 blocks = 1/CU
    size_t p_bytes = (size_t)splitk * Bm * OUT_F * sizeof(unsigned short);
    if (ws_size < a_bytes + w_bytes + p_bytes) {
        splitk = 2;                                        // ws-constrained fallback
        p_bytes = (size_t)splitk * Bm * OUT_F * sizeof(unsigned short);
    }

    if (ws_size >= a_bytes + w_bytes + p_bytes && Bm == 4096) {
        __hip_bfloat16* Apk = (__hip_bfloat16*)d_ws;
        __hip_bfloat16* Wpk = (__hip_bfloat16*)((char*)d_ws + a_bytes);
        unsigned short* P = (unsigned short*)((char*)d_ws + a_bytes + w_bytes);
        const int nb_a = (Bm * IN_F / 8) / 256;            // 2048
        const int nb_w = (OUT_F * IN_F) / 256;             // 4096
        pack_kernel<<<nb_a + nb_w, 256, 0, stream>>>(x, bw, sw, Apk, Wpk, Bm);
        gemm_splitk<<<(Bm / BM) * (OUT_F / BN) * splitk, 512, 0, stream>>>(
            Apk, Wpk, P, Bm, splitk, KDIM / splitk);
        reduce_kernel<<<Bm * OUT_F / 2048, 256, 0, stream>>>(P, out, Bm * OUT_F, splitk);
    } else {
        fallback_kernel<<<dim3(OUT_F / 256, Bm), 256, 0, stream>>>(x, bw, sw, grid, out, Bm);
    }
}

// Round 2
// 197.526 us; speedup vs baseline: 1.0884x; 1.0127x over previous
//
#include <hip/hip_runtime.h>
#include <hip/hip_bf16.h>

#define IN_F 1024
#define OUT_F 1024
#define QP 9                   // silu + 8 spline bases per input feature
#define KDIM (IN_F * QP)       // 9216
#define BM 256
#define BN 256
#define BK 64
#define TILE_SH (BM * BK)      // 16384 shorts = 32 KB per matrix per buffer

typedef __attribute__((ext_vector_type(8)))  short short8;           // MFMA A/B frag (8 bf16)
typedef __attribute__((ext_vector_type(16))) float floatx16;         // 32x32 MFMA C/D frag
typedef __attribute__((ext_vector_type(8)))  unsigned short ushort8v;// 16B bf16 vector

__device__ __forceinline__ unsigned short f2bf(float f) {
    union { float f; unsigned u; } v; v.f = f;
    return (unsigned short)((v.u + 0x7FFF + ((v.u >> 16) & 1)) >> 16); // RNE
}
__device__ __forceinline__ float bf2f(unsigned short h) {
    union { unsigned u; float f; } v; v.u = ((unsigned)h) << 16;
    return v.f;
}

// ============ fused pack: A [B,KDIM] + W [OUT,KDIM], bf16; k = s*IN_F + i ============
// (unchanged)
__global__ __launch_bounds__(256) void pack_kernel(const float* __restrict__ x,
                                                   const float* __restrict__ bw,
                                                   const float* __restrict__ sw,
                                                   __hip_bfloat16* __restrict__ A,
                                                   __hip_bfloat16* __restrict__ W, int Bm) {
    const int nb_a = (Bm * IN_F / 8) / 256;
    if ((int)blockIdx.x < nb_a) {
        int t  = blockIdx.x * 256 + threadIdx.x;   // one thread = 8 features of one row
        int b  = t >> 7;
        int i0 = (t & 127) * 8;
        const float4* xr = (const float4*)(x + (size_t)b * IN_F + i0);
        float4 x0 = xr[0], x1 = xr[1];
        float xv[8] = {x0.x, x0.y, x0.z, x0.w, x1.x, x1.y, x1.z, x1.w};
        ushort8v ov[9];
#pragma unroll
        for (int e = 0; e < 8; ++e) {
            float v  = xv[e];
            float u  = (v + 1.0f) * 5.5f;
            float fj = floorf(u);
            int   j  = (int)fj;
            float tt = u - fj;
            float t2 = tt * tt, t3 = t2 * tt;
            float omt = 1.0f - tt;
            float w0 = omt * omt * omt * (1.0f / 6.0f);                           // q=j-3
            float w1 = (3.0f * t3 - 6.0f * t2 + 4.0f) * (1.0f / 6.0f);            // q=j-2
            float w2 = (-3.0f * t3 + 3.0f * t2 + 3.0f * tt + 1.0f) * (1.0f/6.0f); // q=j-1
            float w3 = t3 * (1.0f / 6.0f);                                        // q=j
            ov[0][e] = f2bf(v * __builtin_amdgcn_rcpf(1.0f + __expf(-v)));        // silu
#pragma unroll
            for (int q = 0; q < 8; ++q) {
                int d = j - q;
                float bv = (d == 3) ? w0 : (d == 2) ? w1 : (d == 1) ? w2 : (d == 0) ? w3 : 0.0f;
                ov[1 + q][e] = f2bf(bv);
            }
        }
        unsigned short* dst = (unsigned short*)A + (size_t)b * KDIM + i0;
#pragma unroll
        for (int s = 0; s < QP; ++s)
            *(ushort8v*)(dst + (size_t)s * IN_F) = ov[s];        // coalesced 16B
    } else {
        int t = ((int)blockIdx.x - nb_a) * 256 + threadIdx.x;    // one (o,i)
        unsigned short* dst = (unsigned short*)W + (size_t)(t >> 10) * KDIM + (t & 1023);
        dst[0] = f2bf(bw[t]);
        const float4* s4 = (const float4*)(sw + (size_t)t * 8);  // 32B contiguous/thread
        float4 lo = s4[0], hi = s4[1];
        dst[1 * IN_F] = f2bf(lo.x); dst[2 * IN_F] = f2bf(lo.y);
        dst[3 * IN_F] = f2bf(lo.z); dst[4 * IN_F] = f2bf(lo.w);
        dst[5 * IN_F] = f2bf(hi.x); dst[6 * IN_F] = f2bf(hi.y);
        dst[7 * IN_F] = f2bf(hi.z); dst[8 * IN_F] = f2bf(hi.w);  // coalesced across lanes
    }
}

// ============ split-K GEMM: 256x256 tile, BK=64, double-buffer, 1 barrier/tile ======
// Schedule (T3-minimum with the vmcnt stall amortized):
//   prologue: STAGE(buf0, tile0)
//   tile t:   vmcnt(0)   <- tile t's 8 loads, issued one FULL tile (~3000cy) ago: free
//             barrier    <- collective residency of tile t; all t-1 reads consumed
//             STAGE(buf^1, tile t+1)   <- 8 GLDs get a whole tile of flight time
//             24 ds_read_b128 + 32 MFMA (compiler-scheduled fine-grained lgkmcnt)
// LDS: row-major [256 rows][8 granules of 16B], 128B rows. 3-bit XOR granule
//   swizzle s(row)=row&7: applied on the GLOBAL source (gload_lds dest linear,
//   m104/m173) and on the ds_read address. Every 8-lane b128 frag-read group
//   (rows 8k..8k+7, fixed logical granule) hits all 32 banks exactly once ->
//   conflict-free by construction (round-0's 0-conflict layout class).
#define GLD(src, dst) __builtin_amdgcn_global_load_lds( \
        (const __attribute__((address_space(1))) void*)(src), \
        (__attribute__((address_space(3))) void*)(dst), 16, 0, 0)

__global__ __launch_bounds__(512, 2) void gemm_splitk(const __hip_bfloat16* __restrict__ A,
                                                      const __hip_bfloat16* __restrict__ W,
                                                      unsigned short* __restrict__ P,
                                                      int Bm, int splitk, int kslice) {
    __shared__ __align__(16) short sA[2][TILE_SH];   // 2 x 32 KB
    __shared__ __align__(16) short sB[2][TILE_SH];   // 2 x 32 KB  (128 KB total)
    const int tid  = threadIdx.x;
    const int lane = tid & 63;
    const int wave = tid >> 6;
    const int r32  = lane & 31;
    const int half = lane >> 5;
    const int wm   = wave >> 2;        // 0..1 : wave rows of 128
    const int wn   = wave & 3;         // 0..3 : wave cols of 64

    // XCD-aware decode (kept from round 1: FETCH 304->83 MB): per-XCD W slice
    // is L2-resident; each A panel shared by only 2 XCDs.
    const int b   = (int)blockIdx.x;
    const int xcd = b & 7, ii = b >> 3;
    const int pp  = xcd * (splitk >> 1) + (ii >> 4);
    const int xt  = pp & 3, zt = pp >> 2, yt = ii & 15;
    const int m0 = yt * BM, n0 = xt * BN, kb = zt * kslice;
    const int NT = kslice / BK;        // 36 (splitk=4) or 72 (splitk=2)

    const short* Ag = (const short*)A + (size_t)m0 * KDIM + kb;
    const short* Wg = (const short*)W + (size_t)n0 * KDIM + kb;

    // staging: 2048 16B-chunks per matrix per tile; chunk c = u*512+tid:
    // row = c>>3, gpos = c&7, LDS dest linear (c*16 B), global source granule
    // pre-swizzled gpos ^ (row&7).
    const short* pA[4]; const short* pB[4]; int ldst[4];
#pragma unroll
    for (int u = 0; u < 4; ++u) {
        int c  = u * 512 + tid;
        int gs = ((c & 7) ^ ((c >> 3) & 7)) * 8;
        pA[u] = Ag + (size_t)(c >> 3) * KDIM + gs;
        pB[u] = Wg + (size_t)(c >> 3) * KDIM + gs;
        ldst[u] = c * 8;
    }

    // fragment ds_read offsets: row = wm*128+mi*32+r32 (row&7 == r32&7),
    // logical granule g = kc*2+half, swizzled: off = row*64 + ((g ^ (r32&7))*8)
    const int sw7 = r32 & 7;
    int offA[4][4], offB[2][4];
#pragma unroll
    for (int mi = 0; mi < 4; ++mi) {
        int row = wm * 128 + mi * 32 + r32;
#pragma unroll
        for (int kc = 0; kc < 4; ++kc)
            offA[mi][kc] = row * BK + (((kc * 2 + half) ^ sw7) * 8);
    }
#pragma unroll
    for (int ni = 0; ni < 2; ++ni) {
        int row = wn * 64 + ni * 32 + r32;
#pragma unroll
        for (int kc = 0; kc < 4; ++kc)
            offB[ni][kc] = row * BK + (((kc * 2 + half) ^ sw7) * 8);
    }

    floatx16 acc[4][2] = {};

#define STAGE(bi, koff) do { \
        _Pragma("unroll") \
        for (int u = 0; u < 4; ++u) { \
            GLD(pA[u] + (koff), &sA[bi][ldst[u]]); \
            GLD(pB[u] + (koff), &sB[bi][ldst[u]]); \
        } \
    } while (0)

    STAGE(0, 0);                                   // tile 0 in flight (8 loads)

    for (int t = 0; t < NT; ++t) {
        // tile t's loads were issued one full tile ago -> near-zero stall
        asm volatile("s_waitcnt vmcnt(0)" ::: "memory");
        __builtin_amdgcn_s_barrier();

        const int nb = (t + 1 == NT) ? 0 : t + 1;  // wrapped (harmless) prefetch
        STAGE((t + 1) & 1, nb * BK);

        const short* sAb = &sA[t & 1][0];
        const short* sBb = &sB[t & 1][0];

        __builtin_amdgcn_s_setprio(1);
#pragma unroll
        for (int kc = 0; kc < 4; ++kc) {
            short8 aF[4], bF[2];
#pragma unroll
            for (int mi = 0; mi < 4; ++mi) aF[mi] = *(const short8*)(sAb + offA[mi][kc]);
#pragma unroll
            for (int ni = 0; ni < 2; ++ni) bF[ni] = *(const short8*)(sBb + offB[ni][kc]);
#pragma unroll
            for (int mi = 0; mi < 4; ++mi)
#pragma unroll
                for (int ni = 0; ni < 2; ++ni)
                    acc[mi][ni] = __builtin_amdgcn_mfma_f32_32x32x16_bf16(
                        aF[mi], bF[ni], acc[mi][ni], 0, 0, 0);
        }
        __builtin_amdgcn_s_setprio(0);
    }
#undef STAGE
    asm volatile("s_waitcnt vmcnt(0)" ::: "memory");   // drain wrapped prefetch

    // C/D layout (m74/m101-verified): col = lane&31, row = (reg&3) + 8*(reg>>2) + 4*(lane>>5)
    unsigned short* Pz = P + (size_t)zt * Bm * OUT_F;
#pragma unroll
    for (int mi = 0; mi < 4; ++mi)
#pragma unroll
        for (int ni = 0; ni < 2; ++ni)
#pragma unroll
            for (int r = 0; r < 16; ++r) {
                int row = (r & 3) + 8 * (r >> 2) + 4 * half;
                int gm  = m0 + wm * 128 + mi * 32 + row;
                Pz[(size_t)gm * OUT_F + n0 + wn * 64 + ni * 32 + r32] = f2bf(acc[mi][ni][r]);
            }
}

// ============ reduce: C = sum_j P_j (bf16 partials -> fp32 out), 8 elems/thread ====
__global__ __launch_bounds__(256) void reduce_kernel(const unsigned short* __restrict__ P,
                                                     float* __restrict__ C, int n, int s) {
    int t  = blockIdx.x * 256 + threadIdx.x;
    int i0 = t * 8;
    float o[8] = {0.f, 0.f, 0.f, 0.f, 0.f, 0.f, 0.f, 0.f};
    for (int j = 0; j < s; ++j) {
        ushort8v a = *(const ushort8v*)(P + (size_t)j * n + i0);
#pragma unroll
        for (int e = 0; e < 8; ++e) o[e] += bf2f(a[e]);
    }
    float4 o0, o1;
    o0.x = o[0]; o0.y = o[1]; o0.z = o[2]; o0.w = o[3];
    o1.x = o[4]; o1.y = o[5]; o1.z = o[6]; o1.w = o[7];
    *(float4*)(C + i0)     = o0;
    *(float4*)(C + i0 + 4) = o1;
}

// ---- fp32 fallback (tiny ws / unexpected shape) ----
__global__ __launch_bounds__(256) void fallback_kernel(const float* __restrict__ x,
                                                       const float* __restrict__ bw,
                                                       const float* __restrict__ sw,
                                                       const float* __restrict__ grid,
                                                       float* __restrict__ out, int Bm) {
    __shared__ float sv[256][QP + 1];
    int b = blockIdx.y;
    int o = blockIdx.x * 256 + threadIdx.x;
    float acc = 0.f;
    for (int ic = 0; ic < IN_F; ic += 256) {
        int i = ic + threadIdx.x;
        float v = x[(size_t)b * IN_F + i];
        float g[12];
        for (int j = 0; j < 12; ++j) g[j] = grid[j];
        float bb[11];
        for (int j = 0; j < 11; ++j) bb[j] = (v >= g[j] && v < g[j + 1]) ? 1.f : 0.f;
        for (int k = 1; k <= 3; ++k)
            for (int j = 0; j < 11 - k; ++j)
                bb[j] = (v - g[j]) / (g[j + k] - g[j] + 1e-8f) * bb[j]
                      + (g[j + k + 1] - v) / (g[j + k + 1] - g[j + 1] + 1e-8f) * bb[j + 1];
        __syncthreads();
        sv[threadIdx.x][0] = v / (1.f + __expf(-v));
        for (int q = 0; q < 8; ++q) sv[threadIdx.x][1 + q] = bb[q];
        __syncthreads();
        for (int ii = 0; ii < 256; ++ii) {
            int i2 = ic + ii;
            acc += sv[ii][0] * bw[(size_t)o * IN_F + i2];
            const float* swp = sw + ((size_t)o * IN_F + i2) * 8;
            for (int q = 0; q < 8; ++q) acc += sv[ii][1 + q] * swp[q];
        }
    }
    out[(size_t)b * OUT_F + o] = acc;
}

extern "C" void kernel_launch(void* const* d_in, const int* in_sizes, int n_in,
                              void* d_out, int out_size, void* d_ws, size_t ws_size,
                              hipStream_t stream) {
    const float* x    = (const float*)d_in[0];
    const float* bw   = (const float*)d_in[1];
    const float* sw   = (const float*)d_in[2];
    const float* grid = (const float*)d_in[3];
    float* out = (float*)d_out;

    const int Bm = in_sizes[0] / IN_F;                     // 4096
    const size_t a_bytes = (size_t)Bm * KDIM * sizeof(__hip_bfloat16);
    const size_t w_bytes = (size_t)OUT_F * KDIM * sizeof(__hip_bfloat16);

    int splitk = 4;                                        // 256 blocks = 1/CU
    size_t p_bytes = (size_t)splitk * Bm * OUT_F * sizeof(unsigned short);
    if (ws_size < a_bytes + w_bytes + p_bytes) {
        splitk = 2;                                        // ws-constrained fallback
        p_bytes = (size_t)splitk * Bm * OUT_F * sizeof(unsigned short);
    }

    if (ws_size >= a_bytes + w_bytes + p_bytes && Bm == 4096) {
        __hip_bfloat16* Apk = (__hip_bfloat16*)d_ws;
        __hip_bfloat16* Wpk = (__hip_bfloat16*)((char*)d_ws + a_bytes);
        unsigned short* P = (unsigned short*)((char*)d_ws + a_bytes + w_bytes);
        const int nb_a = (Bm * IN_F / 8) / 256;            // 2048
        const int nb_w = (OUT_F * IN_F) / 256;             // 4096
        pack_kernel<<<nb_a + nb_w, 256, 0, stream>>>(x, bw, sw, Apk, Wpk, Bm);
        gemm_splitk<<<(Bm / BM) * (OUT_F / BN) * splitk, 512, 0, stream>>>(
            Apk, Wpk, P, Bm, splitk, KDIM / splitk);
        reduce_kernel<<<Bm * OUT_F / 2048, 256, 0, stream>>>(P, out, Bm * OUT_F, splitk);
    } else {
        fallback_kernel<<<dim3(OUT_F / 256, Bm), 256, 0, stream>>>(x, bw, sw, grid, out, Bm);
    }
}